// Round 7
// baseline (202.674 us; speedup 1.0000x reference)
//
#include <hip/hip_runtime.h>
#include <cmath>

#define NDEV   100000
#define NBATCH 8192
#define CONTF  62
#define EMB    16
#define FEAT   94      // 62 + 16 + 16
#define KNBR   64
#define NH     4
#define OUTD   16
#define HOUT   64      // NH*OUTD
#define FUS    204     // 94 + 94 + 16
#define ALPHA  0.2f

#define NDEVG  1563    // ceil(100000/64) row-groups
#define NCOMBG 128     // 8192/64 row-groups
#define XPITCH 95      // 95 % 32 == 31 -> bank permutation, conflict-free reads

typedef unsigned short ushortT;
typedef ushortT ushort8v __attribute__((ext_vector_type(8)));

// ---------------- workspace layout (floats) ----------------
// h_bf : NDEV*64 bf16 = 3,200,000 float-slots @ 0   (12.8 MB)
// e_d  : NDEV*4       =   400,000 @ 3,200,000
// e_c  : NBATCH*4     =    32,768 @ 3,600,000
// fus  : NBATCH*204   = 1,671,168 @ 3,632,768   (row-major [b][204])

template <typename T>
__device__ __forceinline__ const T* uniform_ptr(const T* p) {
  uint64_t v = (uint64_t)(uintptr_t)p;
  uint32_t lo = __builtin_amdgcn_readfirstlane((uint32_t)v);
  uint32_t hi = __builtin_amdgcn_readfirstlane((uint32_t)(v >> 32));
  return (const T*)(uintptr_t)(((uint64_t)hi << 32) | lo);
}

__device__ __forceinline__ float bf2f(ushortT u) {
  return __uint_as_float(((unsigned int)u) << 16);
}
__device__ __forceinline__ ushortT f2bf(float f) {
  unsigned int i = __float_as_uint(f);
  unsigned int r = i + 0x7FFFu + ((i >> 16) & 1u);  // round-to-nearest-even
  return (ushortT)(r >> 16);
}

// 16 FMAs for one feature; Wg = this head's [f][16] slab (uniform address ->
// s_load_dwordx16 feed on the scalar pipe).
__device__ __forceinline__ void fma16(float acc[OUTD], float x,
                                      const float* __restrict__ Wg, int f) {
  const float4* wr = reinterpret_cast<const float4*>(Wg + f * OUTD);
  const float4 w0 = wr[0], w1 = wr[1], w2 = wr[2], w3 = wr[3];
  acc[0]  = fmaf(x, w0.x, acc[0]);  acc[1]  = fmaf(x, w0.y, acc[1]);
  acc[2]  = fmaf(x, w0.z, acc[2]);  acc[3]  = fmaf(x, w0.w, acc[3]);
  acc[4]  = fmaf(x, w1.x, acc[4]);  acc[5]  = fmaf(x, w1.y, acc[5]);
  acc[6]  = fmaf(x, w1.z, acc[6]);  acc[7]  = fmaf(x, w1.w, acc[7]);
  acc[8]  = fmaf(x, w2.x, acc[8]);  acc[9]  = fmaf(x, w2.y, acc[9]);
  acc[10] = fmaf(x, w2.z, acc[10]); acc[11] = fmaf(x, w2.w, acc[11]);
  acc[12] = fmaf(x, w3.x, acc[12]); acc[13] = fmaf(x, w3.y, acc[13]);
  acc[14] = fmaf(x, w3.z, acc[14]); acc[15] = fmaf(x, w3.w, acc[15]);
}

// ---------------- K1: X[row,94] @ W[94,64] ----------------
// Block = 256 thr = 4 waves over the SAME 64-row LDS tile; wave = head.
// X staged once per block (coalesced stream for device rows), W via s_load.
__global__ __launch_bounds__(256, 4) void k_feat(
    const float* __restrict__ device_cont, const int* __restrict__ device_cat,
    const float* __restrict__ de0, const float* __restrict__ de1,
    const float* __restrict__ Wd, const float* __restrict__ bd,
    const float* __restrict__ combin_cont, const int* __restrict__ combin_cat,
    const int* __restrict__ combin_idx,
    const float* __restrict__ ce0, const float* __restrict__ ce1,
    const float* __restrict__ Wc, const float* __restrict__ bc,
    const float* __restrict__ aW,
    ushortT* __restrict__ h_bf, float* __restrict__ e_d, float* __restrict__ e_c) {
  __shared__ float x_s[64 * XPITCH];  // 24,320 B
  __shared__ int   ci_s[64];

  const int tid  = threadIdx.x;
  const int lane = tid & 63;
  const int g = __builtin_amdgcn_readfirstlane((int)(tid >> 6));  // head
  const int blk = blockIdx.x;
  const bool devp = blk < NDEVG;
  const int b0 = (devp ? blk : blk - NDEVG) * 64;

  if (!devp && tid < 64) ci_s[tid] = combin_idx[b0 + tid];
  __syncthreads();

  // ---- stage continuous features: 64*62 = 3968 elements ----
  {
    const float* __restrict__ cont = devp ? device_cont : combin_cont;
#pragma unroll 1
    for (int it = 0; it < 16; ++it) {
      const int e = it * 256 + tid;
      if (e < 64 * CONTF) {
        const int r = e / CONTF, f = e - r * CONTF;
        float v;
        if (devp) {
          const long ge = (long)b0 * CONTF + e;  // contiguous, coalesced
          v = (ge < (long)NDEV * CONTF) ? cont[ge] : 0.f;
        } else {
          v = cont[(size_t)ci_s[r] * CONTF + f];
        }
        x_s[r * XPITCH + f] = v;
      }
    }
  }
  // ---- stage embeddings: 128 threads, one (row, table) each ----
  if (tid < 128) {
    const int r = tid >> 1, h = tid & 1;
    const int srcrow = devp ? min(b0 + r, NDEV - 1) : ci_s[r];
    const int cidx = (devp ? device_cat : combin_cat)[2 * srcrow + h];
    const float* __restrict__ ep =
        (h ? (devp ? de1 : ce1) : (devp ? de0 : ce0)) + (size_t)cidx * EMB;
    float* __restrict__ dst = x_s + r * XPITCH + CONTF + h * EMB;
#pragma unroll
    for (int k4 = 0; k4 < 4; ++k4) {
      const float4 v = reinterpret_cast<const float4*>(ep)[k4];
      dst[4 * k4 + 0] = v.x;
      dst[4 * k4 + 1] = v.y;
      dst[4 * k4 + 2] = v.z;
      dst[4 * k4 + 3] = v.w;
    }
  }
  __syncthreads();

  // ---- compute: wave g, lane = row; x from LDS, W via scalar pipe ----
  const float* Wg = uniform_ptr(devp ? Wd : Wc) + (size_t)g * FEAT * OUTD;
  const float* bg = uniform_ptr(devp ? bd : bc) + g * OUTD;
  const float* ag = uniform_ptr(aW) + g * 2 * OUTD + (devp ? OUTD : 0);

  float acc[OUTD];
#pragma unroll
  for (int o = 0; o < OUTD; ++o) acc[o] = bg[o];

  const float* __restrict__ xr = x_s + lane * XPITCH;
#pragma unroll 2
  for (int f = 0; f < FEAT; f += 2) {
    const float x0 = xr[f], x1 = xr[f + 1];
    fma16(acc, x0, Wg, f);
    fma16(acc, x1, Wg, f + 1);
  }

  // logit from fp32 acc (so softmax weights stay near-exact)
  float ev = 0.f;
#pragma unroll
  for (int o = 0; o < OUTD; ++o) ev = fmaf(acc[o], ag[o], ev);

  const int row = b0 + lane;
  if (devp) {
    if (row < NDEV) {
      ushort8v v0, v1;
#pragma unroll
      for (int o = 0; o < 8; ++o) { v0[o] = f2bf(acc[o]); v1[o] = f2bf(acc[8 + o]); }
      ushort8v* dst = reinterpret_cast<ushort8v*>(h_bf + (size_t)row * HOUT + g * OUTD);
      dst[0] = v0;
      dst[1] = v1;
      e_d[(size_t)row * NH + g] = ev;
    }
  } else {
    e_c[(size_t)row * NH + g] = ev;
  }
}

// ---------------- K2: attention + fusion-row build ----------------
__global__ __launch_bounds__(256, 4) void k_attn(
    const int* __restrict__ neighbor_idx, const int* __restrict__ device_idx,
    const int* __restrict__ device_cat, const float* __restrict__ device_cont,
    const float* __restrict__ de0, const float* __restrict__ de1,
    const int* __restrict__ combin_idx, const int* __restrict__ combin_cat,
    const float* __restrict__ combin_cont,
    const float* __restrict__ ce0, const float* __restrict__ ce1,
    const ushortT* __restrict__ h_bf, const float* __restrict__ e_d,
    const float* __restrict__ e_c, const float* __restrict__ ab,
    const float* __restrict__ W1, const float* __restrict__ b1,
    float* __restrict__ fus) {
  __shared__ __align__(16) float pb[4][NH][68];
  __shared__ __align__(16) int   nb[4][KNBR];
  __shared__ float hb[4][HOUT];
  __shared__ float afb[4][OUTD];

  const int lane = threadIdx.x & 63;
  const int wid  = __builtin_amdgcn_readfirstlane((int)(threadIdx.x >> 6));
  const int b    = blockIdx.x * 4 + wid;

  // ---- phase 1: lane = neighbor k ----
  const int nk = neighbor_idx[(size_t)b * KNBR + lane];
  const float4 ed4 = *reinterpret_cast<const float4*>(e_d + (size_t)nk * NH);
  const float4 ec4 = *reinterpret_cast<const float4*>(e_c + (size_t)b * NH);
  const float4 ab4 = *reinterpret_cast<const float4*>(ab);

  float v0 = ec4.x + ed4.x + ab4.x;
  float v1 = ec4.y + ed4.y + ab4.y;
  float v2 = ec4.z + ed4.z + ab4.z;
  float v3 = ec4.w + ed4.w + ab4.w;
  v0 = v0 > 0.f ? v0 : ALPHA * v0;
  v1 = v1 > 0.f ? v1 : ALPHA * v1;
  v2 = v2 > 0.f ? v2 : ALPHA * v2;
  v3 = v3 > 0.f ? v3 : ALPHA * v3;

  float m0 = v0, m1 = v1, m2 = v2, m3 = v3;
#pragma unroll
  for (int msk = 1; msk < 64; msk <<= 1) {
    m0 = fmaxf(m0, __shfl_xor(m0, msk));
    m1 = fmaxf(m1, __shfl_xor(m1, msk));
    m2 = fmaxf(m2, __shfl_xor(m2, msk));
    m3 = fmaxf(m3, __shfl_xor(m3, msk));
  }
  float p0 = expf(v0 - m0), p1 = expf(v1 - m1), p2 = expf(v2 - m2), p3 = expf(v3 - m3);
  float s0 = p0, s1 = p1, s2 = p2, s3 = p3;
#pragma unroll
  for (int msk = 1; msk < 64; msk <<= 1) {
    s0 += __shfl_xor(s0, msk);
    s1 += __shfl_xor(s1, msk);
    s2 += __shfl_xor(s2, msk);
    s3 += __shfl_xor(s3, msk);
  }
  p0 /= s0; p1 /= s1; p2 /= s2; p3 /= s3;

  pb[wid][0][lane] = p0;
  pb[wid][1][lane] = p1;
  pb[wid][2][lane] = p2;
  pb[wid][3][lane] = p3;
  nb[wid][lane]    = nk;
  __syncthreads();

  // ---- phase 2: lane = (q, c8): q = 8-neighbor group, c8 = column oct ----
  {
    const int q = lane >> 3, c8 = lane & 7;
    const int hq = c8 >> 1;
    float a[8];
#pragma unroll
    for (int i = 0; i < 8; ++i) a[i] = 0.f;
#pragma unroll
    for (int t = 0; t < 8; ++t) {
      const int k   = q * 8 + t;
      const int n   = nb[wid][k];
      const float p = pb[wid][hq][k];
      const ushort8v hv =
          *reinterpret_cast<const ushort8v*>(h_bf + (size_t)n * HOUT + c8 * 8);
#pragma unroll
      for (int i = 0; i < 8; ++i) a[i] = fmaf(p, bf2f(hv[i]), a[i]);
    }
#pragma unroll
    for (int msk = 8; msk < 64; msk <<= 1) {
#pragma unroll
      for (int i = 0; i < 8; ++i) a[i] += __shfl_xor(a[i], msk);
    }
    if (q == 0) {
#pragma unroll
      for (int i = 0; i < 8; ++i) a[i] = a[i] > 0.f ? a[i] : expm1f(a[i]);  // elu
      float4* hp = reinterpret_cast<float4*>(&hb[wid][c8 * 8]);
      hp[0] = make_float4(a[0], a[1], a[2], a[3]);
      hp[1] = make_float4(a[4], a[5], a[6], a[7]);
    }
  }
  __syncthreads();

  // ---- attn_feats = head_out(64) @ W1(64x16) + b1 ----
  {
    const int j = lane & 15, gg = lane >> 4;
    float part = 0.f;
#pragma unroll
    for (int t = 0; t < 16; ++t)
      part = fmaf(hb[wid][gg * 16 + t], W1[(gg * 16 + t) * OUTD + j], part);
    part += __shfl_xor(part, 16);
    part += __shfl_xor(part, 32);
    if (lane < 16) afb[wid][lane] = part + b1[lane];
  }
  __syncthreads();

  // ---- fusion row [comb 94 | dev 94 | att 16], row-major coalesced ----
  const int ci = combin_idx[b];
  const int cc0 = combin_cat[2 * ci], cc1 = combin_cat[2 * ci + 1];
  const int didx = device_idx[b];
  const int dc0 = device_cat[2 * didx], dc1 = device_cat[2 * didx + 1];
  float* __restrict__ frow = fus + (size_t)b * FUS;
#pragma unroll
  for (int t = 0; t < 4; ++t) {
    const int i = lane + t * 64;
    if (i < FUS) {
      float v;
      if (i < 62)       v = combin_cont[(size_t)ci * CONTF + i];
      else if (i < 78)  v = ce0[(size_t)cc0 * EMB + (i - 62)];
      else if (i < 94)  v = ce1[(size_t)cc1 * EMB + (i - 78)];
      else if (i < 156) v = device_cont[(size_t)didx * CONTF + (i - 94)];
      else if (i < 172) v = de0[(size_t)dc0 * EMB + (i - 156)];
      else if (i < 188) v = de1[(size_t)dc1 * EMB + (i - 172)];
      else              v = afb[wid][i - 188];
      frow[i] = v;
    }
  }
}

// ---------------- K3: MLP (204 -> 64 -> 32 -> 1), 8 rows/block, f-split -----
__global__ __launch_bounds__(256) void k_mlp(
    const float* __restrict__ fus,
    const float* __restrict__ W2, const float* __restrict__ b2,
    const float* __restrict__ W3, const float* __restrict__ b3,
    const float* __restrict__ W4, const float* __restrict__ b4,
    float* __restrict__ out) {
  __shared__ __align__(16) float part[4][4][64];  // [wave][r][col]
  __shared__ __align__(16) float x1s[2][4][64];   // [pair][r][col]
  const int tid  = threadIdx.x;
  const int lane = tid & 63;
  const int wid  = __builtin_amdgcn_readfirstlane((int)(tid >> 6));
  const int pair = wid >> 1, half = wid & 1;
  const int r0   = blockIdx.x * 8 + pair * 4;
  const int f0   = half * 102;

  const float* rp0 = uniform_ptr(fus + (size_t)(r0 + 0) * FUS + f0);
  const float* rp1 = uniform_ptr(fus + (size_t)(r0 + 1) * FUS + f0);
  const float* rp2 = uniform_ptr(fus + (size_t)(r0 + 2) * FUS + f0);
  const float* rp3 = uniform_ptr(fus + (size_t)(r0 + 3) * FUS + f0);

  float acc[4];
  const float bj = half ? 0.f : b2[lane];
#pragma unroll
  for (int r = 0; r < 4; ++r) acc[r] = bj;

#pragma unroll 1
  for (int c = 0; c < 17; ++c) {  // 17*6 = 102
#pragma unroll
    for (int k = 0; k < 6; ++k) {
      const int f = c * 6 + k;
      const float wv = W2[(f0 + f) * 64 + lane];
      acc[0] = fmaf(rp0[f], wv, acc[0]);
      acc[1] = fmaf(rp1[f], wv, acc[1]);
      acc[2] = fmaf(rp2[f], wv, acc[2]);
      acc[3] = fmaf(rp3[f], wv, acc[3]);
    }
  }
#pragma unroll
  for (int r = 0; r < 4; ++r) part[wid][r][lane] = acc[r];
  __syncthreads();

  if (half == 0) {
#pragma unroll
    for (int r = 0; r < 4; ++r)
      x1s[pair][r][lane] = fmaxf(part[wid][r][lane] + part[wid + 1][r][lane], 0.f);
  }
  __syncthreads();

  const int row = tid >> 5, m = tid & 31;
  const int pr = row >> 2, rr = row & 3;
  float x2 = b3[m];
#pragma unroll 2
  for (int j4 = 0; j4 < 16; ++j4) {
    const float4 xv = *reinterpret_cast<const float4*>(&x1s[pr][rr][4 * j4]);
    x2 = fmaf(xv.x, W3[(4 * j4 + 0) * 32 + m], x2);
    x2 = fmaf(xv.y, W3[(4 * j4 + 1) * 32 + m], x2);
    x2 = fmaf(xv.z, W3[(4 * j4 + 2) * 32 + m], x2);
    x2 = fmaf(xv.w, W3[(4 * j4 + 3) * 32 + m], x2);
  }
  float p3r = fmaxf(x2, 0.f) * W4[m];
#pragma unroll
  for (int msk = 1; msk < 32; msk <<= 1) p3r += __shfl_xor(p3r, msk);
  if (m == 0) {
    const float z = p3r + b4[0];
    out[(size_t)(blockIdx.x * 8 + row)] = 1.f / (1.f + expf(-z));
  }
}

extern "C" void kernel_launch(void* const* d_in, const int* in_sizes, int n_in,
                              void* d_out, int out_size, void* d_ws, size_t ws_size,
                              hipStream_t stream) {
  const float* combin_cont  = (const float*)d_in[0];
  const int*   combin_cat   = (const int*)d_in[1];
  const float* device_cont  = (const float*)d_in[2];
  const int*   device_cat   = (const int*)d_in[3];
  const int*   combin_idx   = (const int*)d_in[4];
  const int*   device_idx   = (const int*)d_in[5];
  const int*   neighbor_idx = (const int*)d_in[6];
  const float* ce0 = (const float*)d_in[7];
  const float* ce1 = (const float*)d_in[8];
  const float* de0 = (const float*)d_in[9];
  const float* de1 = (const float*)d_in[10];
  const float* Wc  = (const float*)d_in[11];
  const float* bc  = (const float*)d_in[12];
  const float* Wd  = (const float*)d_in[13];
  const float* bd  = (const float*)d_in[14];
  const float* aW  = (const float*)d_in[15];
  const float* ab  = (const float*)d_in[16];
  const float* W1  = (const float*)d_in[17];
  const float* b1  = (const float*)d_in[18];
  const float* W2  = (const float*)d_in[19];
  const float* b2  = (const float*)d_in[20];
  const float* W3  = (const float*)d_in[21];
  const float* b3  = (const float*)d_in[22];
  const float* W4  = (const float*)d_in[23];
  const float* b4  = (const float*)d_in[24];

  float* ws  = (float*)d_ws;
  ushortT* h_bf = (ushortT*)ws;
  float* e_d = ws + 3200000;
  float* e_c = ws + 3600000;
  float* fus = ws + 3632768;

  k_feat<<<NDEVG + NCOMBG, 256, 0, stream>>>(
      device_cont, device_cat, de0, de1, Wd, bd,
      combin_cont, combin_cat, combin_idx, ce0, ce1, Wc, bc, aW,
      h_bf, e_d, e_c);
  k_attn<<<2048, 256, 0, stream>>>(
      neighbor_idx, device_idx, device_cat, device_cont, de0, de1,
      combin_idx, combin_cat, combin_cont, ce0, ce1,
      h_bf, e_d, e_c, ab, W1, b1, fus);
  k_mlp<<<1024, 256, 0, stream>>>(fus, W2, b2, W3, b3, W4, b4, (float*)d_out);
}

// Round 8
// 181.468 us; speedup vs baseline: 1.1169x; 1.1169x over previous
//
#include <hip/hip_runtime.h>
#include <cmath>

#define NDEV   100000
#define NBATCH 8192
#define CONTF  62
#define EMB    16
#define FEAT   94      // 62 + 16 + 16
#define KNBR   64
#define NH     4
#define OUTD   16
#define HOUT   64      // NH*OUTD
#define FUS    204     // 94 + 94 + 16
#define ALPHA  0.2f

#define NDEVG  1563    // ceil(100000/64) row-groups
#define NCOMBG 128     // 8192/64 row-groups
#define KP     48      // K-pairs incl. zero pad (96 bf16 = 48 uints)

typedef unsigned short ushortT;
typedef unsigned int   uintT;
typedef ushortT ushort8v __attribute__((ext_vector_type(8)));
typedef short   short8  __attribute__((ext_vector_type(8)));
typedef float   float4v __attribute__((ext_vector_type(4)));

// ---------------- workspace layout (floats) ----------------
// h_bf : NDEV*64 bf16 = 3,200,000 float-slots @ 0   (12.8 MB)
// e_d  : NDEV*4       =   400,000 @ 3,200,000
// e_c  : NBATCH*4     =    32,768 @ 3,600,000
// fus  : NBATCH*204   = 1,671,168 @ 3,632,768   (row-major [b][204])

template <typename T>
__device__ __forceinline__ const T* uniform_ptr(const T* p) {
  uint64_t v = (uint64_t)(uintptr_t)p;
  uint32_t lo = __builtin_amdgcn_readfirstlane((uint32_t)v);
  uint32_t hi = __builtin_amdgcn_readfirstlane((uint32_t)(v >> 32));
  return (const T*)(uintptr_t)(((uint64_t)hi << 32) | lo);
}

__device__ __forceinline__ float bf2f(ushortT u) {
  return __uint_as_float(((unsigned int)u) << 16);
}
__device__ __forceinline__ ushortT f2bf(float f) {
  unsigned int i = __float_as_uint(f);
  unsigned int r = i + 0x7FFFu + ((i >> 16) & 1u);  // round-to-nearest-even
  return (ushortT)(r >> 16);
}
__device__ __forceinline__ uintT pack2(float lo, float hi) {
  return ((uintT)f2bf(hi) << 16) | (uintT)f2bf(lo);
}

union FragU { uint4 u; short8 s; };

// ---------------- K1: X[row,94] @ W[94,64] via bf16 MFMA ----------------
// Block = 256 thr = 4 waves; 64-row tile. x and W^T staged bf16-packed in LDS.
// Wave w owns rows w*16..w*16+15; computes all 4 col-tiles (ct = head).
// MFMA 16x16x32_bf16: A[m=lane&15][k=q*8+j], B[k=q*8+j][n=lane&15],
// C/D col=lane&15, row=q*4+reg (m89/m91-verified layouts).
__global__ __launch_bounds__(256, 2) void k_feat(
    const float* __restrict__ device_cont, const int* __restrict__ device_cat,
    const float* __restrict__ de0, const float* __restrict__ de1,
    const float* __restrict__ Wd, const float* __restrict__ bd,
    const float* __restrict__ combin_cont, const int* __restrict__ combin_cat,
    const int* __restrict__ combin_idx,
    const float* __restrict__ ce0, const float* __restrict__ ce1,
    const float* __restrict__ Wc, const float* __restrict__ bc,
    const float* __restrict__ aW,
    ushortT* __restrict__ h_bf, float* __restrict__ e_d, float* __restrict__ e_c) {
  __shared__ uintT x_s[64 * KP];  // 12,288 B  [row][kpair] bf16x2
  __shared__ uintT w_s[64 * KP];  // 12,288 B  [col n][kpair] bf16x2 (W^T)
  __shared__ int   ci_s[64];

  const int tid  = threadIdx.x;
  const int lane = tid & 63;
  const int wv = __builtin_amdgcn_readfirstlane((int)(tid >> 6));
  const int blk = blockIdx.x;
  const bool devp = blk < NDEVG;
  const int b0 = (devp ? blk : blk - NDEVG) * 64;

  if (!devp && tid < 64) ci_s[tid] = combin_idx[b0 + tid];

  // ---- stage W transposed: pair (n, p): w_s[n][p] = {W[n,2p], W[n,2p+1]} ----
  {
    const float* __restrict__ Ws = devp ? Wd : Wc;
#pragma unroll 1
    for (int e = tid; e < 64 * 47; e += 256) {
      const int n = e & 63, p = e >> 6;          // 64*47 = 3008
      const int h = n >> 4, o = n & 15;
      const float lo = Ws[(h * FEAT + 2 * p) * OUTD + o];
      const float hi = Ws[(h * FEAT + 2 * p + 1) * OUTD + o];
      w_s[n * KP + p] = pack2(lo, hi);
    }
    if (tid < 64) w_s[tid * KP + 47] = 0u;       // k = 94,95 zero pad
  }
  __syncthreads();                               // ci_s + w_s visible

  // ---- stage x: cont pairs ----
  {
    const float* __restrict__ cont = devp ? device_cont : combin_cont;
#pragma unroll 1
    for (int e = tid; e < 64 * 31; e += 256) {   // 62 cont = 31 pairs
      const int r = e / 31, p = e - r * 31;
      const size_t srow = devp ? (size_t)min(b0 + r, NDEV - 1) : (size_t)ci_s[r];
      const float2 v = *reinterpret_cast<const float2*>(cont + srow * CONTF + 2 * p);
      x_s[r * KP + p] = pack2(v.x, v.y);
    }
  }
  // ---- stage embeddings: thread = (row, table) ----
  if (tid < 128) {
    const int r = tid >> 1, tb = tid & 1;
    const int srow = devp ? min(b0 + r, NDEV - 1) : ci_s[r];
    const int cidx = (devp ? device_cat : combin_cat)[2 * srow + tb];
    const float* __restrict__ ep =
        (tb ? (devp ? de1 : ce1) : (devp ? de0 : ce0)) + (size_t)cidx * EMB;
    uintT* __restrict__ dst = &x_s[r * KP + 31 + tb * 8];
#pragma unroll
    for (int k4 = 0; k4 < 4; ++k4) {
      const float4 v = reinterpret_cast<const float4*>(ep)[k4];
      dst[2 * k4 + 0] = pack2(v.x, v.y);
      dst[2 * k4 + 1] = pack2(v.z, v.w);
    }
  }
  if (tid < 64) x_s[tid * KP + 47] = 0u;         // k = 94,95 zero pad
  __syncthreads();

  // ---- MFMA compute ----
  const int m = lane & 15, q = lane >> 4;
  const float* bias = uniform_ptr(devp ? bd : bc);
  const float* aWl  = uniform_ptr(aW);

  float4v acc[NH];
#pragma unroll
  for (int ct = 0; ct < NH; ++ct) {
    const float bv = bias[ct * OUTD + m];        // C init = bias (col-dependent)
    acc[ct] = (float4v){bv, bv, bv, bv};
  }

  const uintT* xa = &x_s[(wv * 16 + m) * KP + q * 4];
#pragma unroll
  for (int c = 0; c < 3; ++c) {                  // K chunks of 32
    FragU af;
    af.u = *reinterpret_cast<const uint4*>(xa + c * 16);
#pragma unroll
    for (int ct = 0; ct < NH; ++ct) {
      FragU bf;
      bf.u = *reinterpret_cast<const uint4*>(&w_s[(ct * 16 + m) * KP + c * 16 + q * 4]);
      acc[ct] = __builtin_amdgcn_mfma_f32_16x16x32_bf16(af.s, bf.s, acc[ct], 0, 0, 0);
    }
  }

  // ---- epilogue: e logits + h store ----
  const int aoff = devp ? OUTD : 0;
  float* __restrict__ eout = devp ? e_d : e_c;
#pragma unroll
  for (int ct = 0; ct < NH; ++ct) {
    const float av = aWl[ct * 2 * OUTD + aoff + m];
    float e0 = acc[ct][0] * av, e1 = acc[ct][1] * av,
          e2 = acc[ct][2] * av, e3 = acc[ct][3] * av;
#pragma unroll
    for (int msk = 1; msk < 16; msk <<= 1) {     // reduce over o within quad
      e0 += __shfl_xor(e0, msk);
      e1 += __shfl_xor(e1, msk);
      e2 += __shfl_xor(e2, msk);
      e3 += __shfl_xor(e3, msk);
    }
    if (m == ct) {
      const int row = b0 + wv * 16 + q * 4;
      const float ev[4] = {e0, e1, e2, e3};
#pragma unroll
      for (int r = 0; r < 4; ++r)
        if (!devp || row + r < NDEV) eout[(size_t)(row + r) * NH + ct] = ev[r];
    }
  }
  if (devp) {
#pragma unroll
    for (int ct = 0; ct < NH; ++ct) {
#pragma unroll
      for (int r = 0; r < 4; ++r) {
        const int row = b0 + wv * 16 + q * 4 + r;
        if (row < NDEV)
          h_bf[(size_t)row * HOUT + ct * OUTD + m] = f2bf(acc[ct][r]);
      }
    }
  }
}

// ---------------- K2: attention + fusion-row build (unchanged R6) ----------
__global__ __launch_bounds__(256, 4) void k_attn(
    const int* __restrict__ neighbor_idx, const int* __restrict__ device_idx,
    const int* __restrict__ device_cat, const float* __restrict__ device_cont,
    const float* __restrict__ de0, const float* __restrict__ de1,
    const int* __restrict__ combin_idx, const int* __restrict__ combin_cat,
    const float* __restrict__ combin_cont,
    const float* __restrict__ ce0, const float* __restrict__ ce1,
    const ushortT* __restrict__ h_bf, const float* __restrict__ e_d,
    const float* __restrict__ e_c, const float* __restrict__ ab,
    const float* __restrict__ W1, const float* __restrict__ b1,
    float* __restrict__ fus) {
  __shared__ __align__(16) float pb[4][NH][68];
  __shared__ __align__(16) int   nb[4][KNBR];
  __shared__ float hb[4][HOUT];
  __shared__ float afb[4][OUTD];

  const int lane = threadIdx.x & 63;
  const int wid  = __builtin_amdgcn_readfirstlane((int)(threadIdx.x >> 6));
  const int b    = blockIdx.x * 4 + wid;

  const int nk = neighbor_idx[(size_t)b * KNBR + lane];
  const float4 ed4 = *reinterpret_cast<const float4*>(e_d + (size_t)nk * NH);
  const float4 ec4 = *reinterpret_cast<const float4*>(e_c + (size_t)b * NH);
  const float4 ab4 = *reinterpret_cast<const float4*>(ab);

  float v0 = ec4.x + ed4.x + ab4.x;
  float v1 = ec4.y + ed4.y + ab4.y;
  float v2 = ec4.z + ed4.z + ab4.z;
  float v3 = ec4.w + ed4.w + ab4.w;
  v0 = v0 > 0.f ? v0 : ALPHA * v0;
  v1 = v1 > 0.f ? v1 : ALPHA * v1;
  v2 = v2 > 0.f ? v2 : ALPHA * v2;
  v3 = v3 > 0.f ? v3 : ALPHA * v3;

  float m0 = v0, m1 = v1, m2 = v2, m3 = v3;
#pragma unroll
  for (int msk = 1; msk < 64; msk <<= 1) {
    m0 = fmaxf(m0, __shfl_xor(m0, msk));
    m1 = fmaxf(m1, __shfl_xor(m1, msk));
    m2 = fmaxf(m2, __shfl_xor(m2, msk));
    m3 = fmaxf(m3, __shfl_xor(m3, msk));
  }
  float p0 = expf(v0 - m0), p1 = expf(v1 - m1), p2 = expf(v2 - m2), p3 = expf(v3 - m3);
  float s0 = p0, s1 = p1, s2 = p2, s3 = p3;
#pragma unroll
  for (int msk = 1; msk < 64; msk <<= 1) {
    s0 += __shfl_xor(s0, msk);
    s1 += __shfl_xor(s1, msk);
    s2 += __shfl_xor(s2, msk);
    s3 += __shfl_xor(s3, msk);
  }
  p0 /= s0; p1 /= s1; p2 /= s2; p3 /= s3;

  pb[wid][0][lane] = p0;
  pb[wid][1][lane] = p1;
  pb[wid][2][lane] = p2;
  pb[wid][3][lane] = p3;
  nb[wid][lane]    = nk;
  __syncthreads();

  {
    const int q = lane >> 3, c8 = lane & 7;
    const int hq = c8 >> 1;
    float a[8];
#pragma unroll
    for (int i = 0; i < 8; ++i) a[i] = 0.f;
#pragma unroll
    for (int t = 0; t < 8; ++t) {
      const int k   = q * 8 + t;
      const int n   = nb[wid][k];
      const float p = pb[wid][hq][k];
      const ushort8v hv =
          *reinterpret_cast<const ushort8v*>(h_bf + (size_t)n * HOUT + c8 * 8);
#pragma unroll
      for (int i = 0; i < 8; ++i) a[i] = fmaf(p, bf2f(hv[i]), a[i]);
    }
#pragma unroll
    for (int msk = 8; msk < 64; msk <<= 1) {
#pragma unroll
      for (int i = 0; i < 8; ++i) a[i] += __shfl_xor(a[i], msk);
    }
    if (q == 0) {
#pragma unroll
      for (int i = 0; i < 8; ++i) a[i] = a[i] > 0.f ? a[i] : expm1f(a[i]);  // elu
      float4* hp = reinterpret_cast<float4*>(&hb[wid][c8 * 8]);
      hp[0] = make_float4(a[0], a[1], a[2], a[3]);
      hp[1] = make_float4(a[4], a[5], a[6], a[7]);
    }
  }
  __syncthreads();

  {
    const int j = lane & 15, gg = lane >> 4;
    float part = 0.f;
#pragma unroll
    for (int t = 0; t < 16; ++t)
      part = fmaf(hb[wid][gg * 16 + t], W1[(gg * 16 + t) * OUTD + j], part);
    part += __shfl_xor(part, 16);
    part += __shfl_xor(part, 32);
    if (lane < 16) afb[wid][lane] = part + b1[lane];
  }
  __syncthreads();

  const int ci = combin_idx[b];
  const int cc0 = combin_cat[2 * ci], cc1 = combin_cat[2 * ci + 1];
  const int didx = device_idx[b];
  const int dc0 = device_cat[2 * didx], dc1 = device_cat[2 * didx + 1];
  float* __restrict__ frow = fus + (size_t)b * FUS;
#pragma unroll
  for (int t = 0; t < 4; ++t) {
    const int i = lane + t * 64;
    if (i < FUS) {
      float v;
      if (i < 62)       v = combin_cont[(size_t)ci * CONTF + i];
      else if (i < 78)  v = ce0[(size_t)cc0 * EMB + (i - 62)];
      else if (i < 94)  v = ce1[(size_t)cc1 * EMB + (i - 78)];
      else if (i < 156) v = device_cont[(size_t)didx * CONTF + (i - 94)];
      else if (i < 172) v = de0[(size_t)dc0 * EMB + (i - 156)];
      else if (i < 188) v = de1[(size_t)dc1 * EMB + (i - 172)];
      else              v = afb[wid][i - 188];
      frow[i] = v;
    }
  }
}

// ---------------- K3: MLP (204 -> 64 -> 32 -> 1), unchanged R6 ----------------
__global__ __launch_bounds__(256) void k_mlp(
    const float* __restrict__ fus,
    const float* __restrict__ W2, const float* __restrict__ b2,
    const float* __restrict__ W3, const float* __restrict__ b3,
    const float* __restrict__ W4, const float* __restrict__ b4,
    float* __restrict__ out) {
  __shared__ __align__(16) float part[4][4][64];
  __shared__ __align__(16) float x1s[2][4][64];
  const int tid  = threadIdx.x;
  const int lane = tid & 63;
  const int wid  = __builtin_amdgcn_readfirstlane((int)(tid >> 6));
  const int pair = wid >> 1, half = wid & 1;
  const int r0   = blockIdx.x * 8 + pair * 4;
  const int f0   = half * 102;

  const float* rp0 = uniform_ptr(fus + (size_t)(r0 + 0) * FUS + f0);
  const float* rp1 = uniform_ptr(fus + (size_t)(r0 + 1) * FUS + f0);
  const float* rp2 = uniform_ptr(fus + (size_t)(r0 + 2) * FUS + f0);
  const float* rp3 = uniform_ptr(fus + (size_t)(r0 + 3) * FUS + f0);

  float acc[4];
  const float bj = half ? 0.f : b2[lane];
#pragma unroll
  for (int r = 0; r < 4; ++r) acc[r] = bj;

#pragma unroll 1
  for (int c = 0; c < 17; ++c) {
#pragma unroll
    for (int k = 0; k < 6; ++k) {
      const int f = c * 6 + k;
      const float wv = W2[(f0 + f) * 64 + lane];
      acc[0] = fmaf(rp0[f], wv, acc[0]);
      acc[1] = fmaf(rp1[f], wv, acc[1]);
      acc[2] = fmaf(rp2[f], wv, acc[2]);
      acc[3] = fmaf(rp3[f], wv, acc[3]);
    }
  }
#pragma unroll
  for (int r = 0; r < 4; ++r) part[wid][r][lane] = acc[r];
  __syncthreads();

  if (half == 0) {
#pragma unroll
    for (int r = 0; r < 4; ++r)
      x1s[pair][r][lane] = fmaxf(part[wid][r][lane] + part[wid + 1][r][lane], 0.f);
  }
  __syncthreads();

  const int row = tid >> 5, m = tid & 31;
  const int pr = row >> 2, rr = row & 3;
  float x2 = b3[m];
#pragma unroll 2
  for (int j4 = 0; j4 < 16; ++j4) {
    const float4 xv = *reinterpret_cast<const float4*>(&x1s[pr][rr][4 * j4]);
    x2 = fmaf(xv.x, W3[(4 * j4 + 0) * 32 + m], x2);
    x2 = fmaf(xv.y, W3[(4 * j4 + 1) * 32 + m], x2);
    x2 = fmaf(xv.z, W3[(4 * j4 + 2) * 32 + m], x2);
    x2 = fmaf(xv.w, W3[(4 * j4 + 3) * 32 + m], x2);
  }
  float p3r = fmaxf(x2, 0.f) * W4[m];
#pragma unroll
  for (int msk = 1; msk < 32; msk <<= 1) p3r += __shfl_xor(p3r, msk);
  if (m == 0) {
    const float z = p3r + b4[0];
    out[(size_t)(blockIdx.x * 8 + row)] = 1.f / (1.f + expf(-z));
  }
}

extern "C" void kernel_launch(void* const* d_in, const int* in_sizes, int n_in,
                              void* d_out, int out_size, void* d_ws, size_t ws_size,
                              hipStream_t stream) {
  const float* combin_cont  = (const float*)d_in[0];
  const int*   combin_cat   = (const int*)d_in[1];
  const float* device_cont  = (const float*)d_in[2];
  const int*   device_cat   = (const int*)d_in[3];
  const int*   combin_idx   = (const int*)d_in[4];
  const int*   device_idx   = (const int*)d_in[5];
  const int*   neighbor_idx = (const int*)d_in[6];
  const float* ce0 = (const float*)d_in[7];
  const float* ce1 = (const float*)d_in[8];
  const float* de0 = (const float*)d_in[9];
  const float* de1 = (const float*)d_in[10];
  const float* Wc  = (const float*)d_in[11];
  const float* bc  = (const float*)d_in[12];
  const float* Wd  = (const float*)d_in[13];
  const float* bd  = (const float*)d_in[14];
  const float* aW  = (const float*)d_in[15];
  const float* ab  = (const float*)d_in[16];
  const float* W1  = (const float*)d_in[17];
  const float* b1  = (const float*)d_in[18];
  const float* W2  = (const float*)d_in[19];
  const float* b2  = (const float*)d_in[20];
  const float* W3  = (const float*)d_in[21];
  const float* b3  = (const float*)d_in[22];
  const float* W4  = (const float*)d_in[23];
  const float* b4  = (const float*)d_in[24];

  float* ws  = (float*)d_ws;
  ushortT* h_bf = (ushortT*)ws;
  float* e_d = ws + 3200000;
  float* e_c = ws + 3600000;
  float* fus = ws + 3632768;

  k_feat<<<NDEVG + NCOMBG, 256, 0, stream>>>(
      device_cont, device_cat, de0, de1, Wd, bd,
      combin_cont, combin_cat, combin_idx, ce0, ce1, Wc, bc, aW,
      h_bf, e_d, e_c);
  k_attn<<<2048, 256, 0, stream>>>(
      neighbor_idx, device_idx, device_cat, device_cont, de0, de1,
      combin_idx, combin_cat, combin_cont, ce0, ce1,
      h_bf, e_d, e_c, ab, W1, b1, fus);
  k_mlp<<<1024, 256, 0, stream>>>(fus, W2, b2, W3, b3, W4, b4, (float*)d_out);
}

// Round 10
// 166.999 us; speedup vs baseline: 1.2136x; 1.0866x over previous
//
#include <hip/hip_runtime.h>
#include <cmath>

#define NDEV   100000
#define NBATCH 8192
#define CONTF  62
#define EMB    16
#define FEAT   94      // 62 + 16 + 16
#define KNBR   64
#define NH     4
#define OUTD   16
#define HOUT   64      // NH*OUTD
#define FUS    204     // 94 + 94 + 16
#define ALPHA  0.2f

#define NDEVG  1563    // ceil(100000/64) row-groups
#define NCOMBG 128     // 8192/64 row-groups
#define KP     48      // K-pairs incl. zero pad (96 bf16 = 48 uints)

typedef unsigned short ushortT;
typedef unsigned int   uintT;
typedef ushortT ushort8v __attribute__((ext_vector_type(8)));
typedef short   short8  __attribute__((ext_vector_type(8)));
typedef float   float4v __attribute__((ext_vector_type(4)));

// ---------------- workspace layout (float slots) ----------------
// h_bf  : NDEV*64 bf16 = 3,200,000 @ 0   (12.8 MB)
// e_d   : NDEV*4       =   400,000 @ 3,200,000
// e_c   : NBATCH*4     =    32,768 @ 3,600,000
// wpack : 2*64*48 uint =     6,144 @ 3,632,768   (bf16x2-packed W^T, dev|comb)

template <typename T>
__device__ __forceinline__ const T* uniform_ptr(const T* p) {
  uint64_t v = (uint64_t)(uintptr_t)p;
  uint32_t lo = __builtin_amdgcn_readfirstlane((uint32_t)v);
  uint32_t hi = __builtin_amdgcn_readfirstlane((uint32_t)(v >> 32));
  return (const T*)(uintptr_t)(((uint64_t)hi << 32) | lo);
}

__device__ __forceinline__ float bf2f(ushortT u) {
  return __uint_as_float(((unsigned int)u) << 16);
}
__device__ __forceinline__ ushortT f2bf(float f) {
  unsigned int i = __float_as_uint(f);
  unsigned int r = i + 0x7FFFu + ((i >> 16) & 1u);  // round-to-nearest-even
  return (ushortT)(r >> 16);
}
__device__ __forceinline__ uintT pack2(float lo, float hi) {
  return ((uintT)f2bf(hi) << 16) | (uintT)f2bf(lo);
}

union FragU { uint4 u; short8 s; };

// ---------------- K0: pack W^T -> bf16x2 once (layout [n][p], n=h*16+o) -----
__global__ __launch_bounds__(256) void k_prep(
    const float* __restrict__ Wd, const float* __restrict__ Wc,
    uintT* __restrict__ wpack) {
  const int e = blockIdx.x * 256 + threadIdx.x;   // 0..6143
  if (e >= 2 * 64 * KP) return;
  const bool dev = e < 64 * KP;
  const int i = dev ? e : e - 64 * KP;
  const int n = i / KP, p = i - n * KP;
  const int h = n >> 4, o = n & 15;
  const float* __restrict__ Ws = dev ? Wd : Wc;
  uintT v = 0u;
  if (p < 47) {
    const float lo = Ws[(h * FEAT + 2 * p) * OUTD + o];
    const float hi = Ws[(h * FEAT + 2 * p + 1) * OUTD + o];
    v = pack2(lo, hi);
  }
  wpack[e] = v;
}

// ---------------- K1: X[row,94] @ W[94,64] via bf16 MFMA ----------------
__global__ __launch_bounds__(256, 2) void k_feat(
    const float* __restrict__ device_cont, const int* __restrict__ device_cat,
    const float* __restrict__ de0, const float* __restrict__ de1,
    const float* __restrict__ bd,
    const float* __restrict__ combin_cont, const int* __restrict__ combin_cat,
    const int* __restrict__ combin_idx,
    const float* __restrict__ ce0, const float* __restrict__ ce1,
    const float* __restrict__ bc,
    const float* __restrict__ aW, const uintT* __restrict__ wpack,
    ushortT* __restrict__ h_bf, float* __restrict__ e_d, float* __restrict__ e_c) {
  __shared__ uintT x_s[64 * KP];  // 12,288 B  [row][kpair]
  __shared__ uintT w_s[64 * KP];  // 12,288 B  [col n][kpair] (prepacked W^T)
  __shared__ int   ci_s[64];

  const int tid  = threadIdx.x;
  const int lane = tid & 63;
  const int wv = __builtin_amdgcn_readfirstlane((int)(tid >> 6));
  const int blk = blockIdx.x;
  const bool devp = blk < NDEVG;
  const int b0 = (devp ? blk : blk - NDEVG) * 64;

  if (!devp && tid < 64) ci_s[tid] = combin_idx[b0 + tid];

  // ---- stage W: linear uint4 copy of the prepacked slab (768 uint4) ----
  {
    const uint4* __restrict__ wp =
        reinterpret_cast<const uint4*>(wpack + (devp ? 0 : 64 * KP));
#pragma unroll
    for (int t = 0; t < 3; ++t)
      reinterpret_cast<uint4*>(w_s)[t * 256 + tid] = wp[t * 256 + tid];
  }
  __syncthreads();  // ci_s visible

  // ---- stage x: cont pairs ----
  {
    const float* __restrict__ cont = devp ? device_cont : combin_cont;
#pragma unroll 1
    for (int e = tid; e < 64 * 31; e += 256) {   // 62 cont = 31 pairs
      const int r = e / 31, p = e - r * 31;
      const size_t srow = devp ? (size_t)min(b0 + r, NDEV - 1) : (size_t)ci_s[r];
      const float2 v = *reinterpret_cast<const float2*>(cont + srow * CONTF + 2 * p);
      x_s[r * KP + p] = pack2(v.x, v.y);
    }
  }
  // ---- stage embeddings: thread = (row, table) ----
  if (tid < 128) {
    const int r = tid >> 1, tb = tid & 1;
    const int srow = devp ? min(b0 + r, NDEV - 1) : ci_s[r];
    const int cidx = (devp ? device_cat : combin_cat)[2 * srow + tb];
    const float* __restrict__ ep =
        (tb ? (devp ? de1 : ce1) : (devp ? de0 : ce0)) + (size_t)cidx * EMB;
    uintT* __restrict__ dst = &x_s[r * KP + 31 + tb * 8];
#pragma unroll
    for (int k4 = 0; k4 < 4; ++k4) {
      const float4 v = reinterpret_cast<const float4*>(ep)[k4];
      dst[2 * k4 + 0] = pack2(v.x, v.y);
      dst[2 * k4 + 1] = pack2(v.z, v.w);
    }
  }
  if (tid < 64) x_s[tid * KP + 47] = 0u;         // k = 94,95 zero pad
  __syncthreads();

  // ---- MFMA compute: wave wv owns rows wv*16..+15, all 4 col-tiles ----
  const int m = lane & 15, q = lane >> 4;
  const float* bias = uniform_ptr(devp ? bd : bc);
  const float* aWl  = uniform_ptr(aW);

  float4v acc[NH];
#pragma unroll
  for (int ct = 0; ct < NH; ++ct) {
    const float bv = bias[ct * OUTD + m];
    acc[ct] = (float4v){bv, bv, bv, bv};
  }

  const uintT* xa = &x_s[(wv * 16 + m) * KP + q * 4];
#pragma unroll
  for (int c = 0; c < 3; ++c) {                  // K chunks of 32
    FragU af;
    af.u = *reinterpret_cast<const uint4*>(xa + c * 16);
#pragma unroll
    for (int ct = 0; ct < NH; ++ct) {
      FragU bf;
      bf.u = *reinterpret_cast<const uint4*>(&w_s[(ct * 16 + m) * KP + c * 16 + q * 4]);
      acc[ct] = __builtin_amdgcn_mfma_f32_16x16x32_bf16(af.s, bf.s, acc[ct], 0, 0, 0);
    }
  }

  // ---- epilogue: e logits + h store ----
  const int aoff = devp ? OUTD : 0;
  float* __restrict__ eout = devp ? e_d : e_c;
#pragma unroll
  for (int ct = 0; ct < NH; ++ct) {
    const float av = aWl[ct * 2 * OUTD + aoff + m];
    float e0 = acc[ct][0] * av, e1 = acc[ct][1] * av,
          e2 = acc[ct][2] * av, e3 = acc[ct][3] * av;
#pragma unroll
    for (int msk = 1; msk < 16; msk <<= 1) {
      e0 += __shfl_xor(e0, msk);
      e1 += __shfl_xor(e1, msk);
      e2 += __shfl_xor(e2, msk);
      e3 += __shfl_xor(e3, msk);
    }
    if (m == ct) {
      const int row = b0 + wv * 16 + q * 4;
      const float ev[4] = {e0, e1, e2, e3};
#pragma unroll
      for (int r = 0; r < 4; ++r)
        if (!devp || row + r < NDEV) eout[(size_t)(row + r) * NH + ct] = ev[r];
    }
  }
  if (devp) {
#pragma unroll
    for (int ct = 0; ct < NH; ++ct) {
#pragma unroll
      for (int r = 0; r < 4; ++r) {
        const int row = b0 + wv * 16 + q * 4 + r;
        if (row < NDEV)
          h_bf[(size_t)row * HOUT + ct * OUTD + m] = f2bf(acc[ct][r]);
      }
    }
  }
}

// ---------------- K2: attention + fusion + MLP, fused (one wave = one row) --
__global__ __launch_bounds__(256, 4) void k_attn(
    const int* __restrict__ neighbor_idx, const int* __restrict__ device_idx,
    const int* __restrict__ device_cat, const float* __restrict__ device_cont,
    const float* __restrict__ de0, const float* __restrict__ de1,
    const int* __restrict__ combin_idx, const int* __restrict__ combin_cat,
    const float* __restrict__ combin_cont,
    const float* __restrict__ ce0, const float* __restrict__ ce1,
    const ushortT* __restrict__ h_bf, const float* __restrict__ e_d,
    const float* __restrict__ e_c, const float* __restrict__ ab,
    const float* __restrict__ W1, const float* __restrict__ b1,
    const float* __restrict__ W2, const float* __restrict__ b2,
    const float* __restrict__ W3, const float* __restrict__ b3,
    const float* __restrict__ W4, const float* __restrict__ b4,
    float* __restrict__ out) {
  __shared__ __align__(16) float pb[4][NH][68];
  __shared__ __align__(16) int   nb[4][KNBR];
  __shared__ __align__(16) float hb[4][HOUT];
  __shared__ __align__(16) float fusb[4][208];   // fusion row (204 + pad)
  __shared__ __align__(16) float x1b[4][64];

  const int lane = threadIdx.x & 63;
  const int wid  = __builtin_amdgcn_readfirstlane((int)(threadIdx.x >> 6));
  const int b    = blockIdx.x * 4 + wid;

  // ---- phase A: softmax over neighbors (lane = k) ----
  const int nk = neighbor_idx[(size_t)b * KNBR + lane];
  const float4 ed4 = *reinterpret_cast<const float4*>(e_d + (size_t)nk * NH);
  const float4 ec4 = *reinterpret_cast<const float4*>(e_c + (size_t)b * NH);
  const float4 ab4 = *reinterpret_cast<const float4*>(ab);

  float v0 = ec4.x + ed4.x + ab4.x;
  float v1 = ec4.y + ed4.y + ab4.y;
  float v2 = ec4.z + ed4.z + ab4.z;
  float v3 = ec4.w + ed4.w + ab4.w;
  v0 = v0 > 0.f ? v0 : ALPHA * v0;
  v1 = v1 > 0.f ? v1 : ALPHA * v1;
  v2 = v2 > 0.f ? v2 : ALPHA * v2;
  v3 = v3 > 0.f ? v3 : ALPHA * v3;

  float m0 = v0, m1 = v1, m2 = v2, m3 = v3;
#pragma unroll
  for (int msk = 1; msk < 64; msk <<= 1) {
    m0 = fmaxf(m0, __shfl_xor(m0, msk));
    m1 = fmaxf(m1, __shfl_xor(m1, msk));
    m2 = fmaxf(m2, __shfl_xor(m2, msk));
    m3 = fmaxf(m3, __shfl_xor(m3, msk));
  }
  float p0 = expf(v0 - m0), p1 = expf(v1 - m1), p2 = expf(v2 - m2), p3 = expf(v3 - m3);
  float s0 = p0, s1 = p1, s2 = p2, s3 = p3;
#pragma unroll
  for (int msk = 1; msk < 64; msk <<= 1) {
    s0 += __shfl_xor(s0, msk);
    s1 += __shfl_xor(s1, msk);
    s2 += __shfl_xor(s2, msk);
    s3 += __shfl_xor(s3, msk);
  }
  p0 /= s0; p1 /= s1; p2 /= s2; p3 /= s3;

  pb[wid][0][lane] = p0;
  pb[wid][1][lane] = p1;
  pb[wid][2][lane] = p2;
  pb[wid][3][lane] = p3;
  nb[wid][lane]    = nk;

  // ---- phase A2: gather fusion features [comb 94 | dev 94] into LDS ----
  const int ci = combin_idx[b];
  const int cc0 = combin_cat[2 * ci], cc1 = combin_cat[2 * ci + 1];
  const int didx = device_idx[b];
  const int dc0 = device_cat[2 * didx], dc1 = device_cat[2 * didx + 1];
#pragma unroll
  for (int t = 0; t < 3; ++t) {
    const int i = lane + t * 64;
    if (i < 188) {
      float v;
      if (i < 62)       v = combin_cont[(size_t)ci * CONTF + i];
      else if (i < 78)  v = ce0[(size_t)cc0 * EMB + (i - 62)];
      else if (i < 94)  v = ce1[(size_t)cc1 * EMB + (i - 78)];
      else if (i < 156) v = device_cont[(size_t)didx * CONTF + (i - 94)];
      else if (i < 172) v = de0[(size_t)dc0 * EMB + (i - 156)];
      else              v = de1[(size_t)dc1 * EMB + (i - 172)];
      fusb[wid][i] = v;
    }
  }
  __syncthreads();

  // ---- phase B: h_bf gather, lane = (q, c8) ----
  {
    const int q = lane >> 3, c8 = lane & 7;
    const int hq = c8 >> 1;
    float a[8];
#pragma unroll
    for (int i = 0; i < 8; ++i) a[i] = 0.f;
#pragma unroll
    for (int t = 0; t < 8; ++t) {
      const int k   = q * 8 + t;
      const int n   = nb[wid][k];
      const float p = pb[wid][hq][k];
      const ushort8v hv =
          *reinterpret_cast<const ushort8v*>(h_bf + (size_t)n * HOUT + c8 * 8);
#pragma unroll
      for (int i = 0; i < 8; ++i) a[i] = fmaf(p, bf2f(hv[i]), a[i]);
    }
#pragma unroll
    for (int msk = 8; msk < 64; msk <<= 1) {
#pragma unroll
      for (int i = 0; i < 8; ++i) a[i] += __shfl_xor(a[i], msk);
    }
    if (q == 0) {
#pragma unroll
      for (int i = 0; i < 8; ++i) a[i] = a[i] > 0.f ? a[i] : expm1f(a[i]);  // elu
      float4* hp = reinterpret_cast<float4*>(&hb[wid][c8 * 8]);
      hp[0] = make_float4(a[0], a[1], a[2], a[3]);
      hp[1] = make_float4(a[4], a[5], a[6], a[7]);
    }
  }
  __syncthreads();

  // ---- phase C: attn_feats = head_out(64) @ W1(64x16) + b1 -> fusb[188..] --
  {
    const int j = lane & 15, gg = lane >> 4;
    float part = 0.f;
#pragma unroll
    for (int t = 0; t < 16; ++t)
      part = fmaf(hb[wid][gg * 16 + t], W1[(gg * 16 + t) * OUTD + j], part);
    part += __shfl_xor(part, 16);
    part += __shfl_xor(part, 32);
    if (lane < 16) fusb[wid][188 + lane] = part + b1[lane];
  }
  __syncthreads();

  // ---- phase D: MLP layer 1 (204 -> 64), lane = output col ----
  float acc = b2[lane];
#pragma unroll 4
  for (int f = 0; f < FUS; ++f)
    acc = fmaf(fusb[wid][f], W2[f * 64 + lane], acc);  // ds broadcast + coalesced
  x1b[wid][lane] = fmaxf(acc, 0.f);
  // wave-local LDS round-trip: compiler inserts lgkmcnt wait, no barrier

  // ---- layers 2+3 + sigmoid ----
  const int m = lane & 31, rh = lane >> 5;
  float x2 = rh ? 0.f : b3[m];
#pragma unroll 4
  for (int j = 0; j < 32; ++j) {
    const int jj = rh * 32 + j;
    x2 = fmaf(x1b[wid][jj], W3[jj * 32 + m], x2);
  }
  x2 += __shfl_xor(x2, 32);                      // combine j-halves
  float pL3 = fmaxf(x2, 0.f) * W4[m];
#pragma unroll
  for (int msk = 1; msk < 32; msk <<= 1) pL3 += __shfl_xor(pL3, msk);
  if (lane == 0) {
    const float z = pL3 + b4[0];
    out[b] = 1.f / (1.f + expf(-z));
  }
}

extern "C" void kernel_launch(void* const* d_in, const int* in_sizes, int n_in,
                              void* d_out, int out_size, void* d_ws, size_t ws_size,
                              hipStream_t stream) {
  const float* combin_cont  = (const float*)d_in[0];
  const int*   combin_cat   = (const int*)d_in[1];
  const float* device_cont  = (const float*)d_in[2];
  const int*   device_cat   = (const int*)d_in[3];
  const int*   combin_idx   = (const int*)d_in[4];
  const int*   device_idx   = (const int*)d_in[5];
  const int*   neighbor_idx = (const int*)d_in[6];
  const float* ce0 = (const float*)d_in[7];
  const float* ce1 = (const float*)d_in[8];
  const float* de0 = (const float*)d_in[9];
  const float* de1 = (const float*)d_in[10];
  const float* Wc  = (const float*)d_in[11];
  const float* bc  = (const float*)d_in[12];
  const float* Wd  = (const float*)d_in[13];
  const float* bd  = (const float*)d_in[14];
  const float* aW  = (const float*)d_in[15];
  const float* ab  = (const float*)d_in[16];
  const float* W1  = (const float*)d_in[17];
  const float* b1  = (const float*)d_in[18];
  const float* W2  = (const float*)d_in[19];
  const float* b2  = (const float*)d_in[20];
  const float* W3  = (const float*)d_in[21];
  const float* b3  = (const float*)d_in[22];
  const float* W4  = (const float*)d_in[23];
  const float* b4  = (const float*)d_in[24];

  float* ws  = (float*)d_ws;
  ushortT* h_bf = (ushortT*)ws;
  float* e_d = ws + 3200000;
  float* e_c = ws + 3600000;
  uintT* wpack = (uintT*)(ws + 3632768);

  k_prep<<<24, 256, 0, stream>>>(Wd, Wc, wpack);
  k_feat<<<NDEVG + NCOMBG, 256, 0, stream>>>(
      device_cont, device_cat, de0, de1, bd,
      combin_cont, combin_cat, combin_idx, ce0, ce1, bc, aW, wpack,
      h_bf, e_d, e_c);
  k_attn<<<2048, 256, 0, stream>>>(
      neighbor_idx, device_idx, device_cat, device_cont, de0, de1,
      combin_idx, combin_cat, combin_cont, ce0, ce1,
      h_bf, e_d, e_c, ab, W1, b1, W2, b2, W3, b3, W4, b4, (float*)d_out);
}

// Round 11
// 165.919 us; speedup vs baseline: 1.2215x; 1.0065x over previous
//
#include <hip/hip_runtime.h>
#include <cmath>

#define NDEV   100000
#define NBATCH 8192
#define CONTF  62
#define EMB    16
#define FEAT   94      // 62 + 16 + 16
#define KNBR   64
#define NH     4
#define OUTD   16
#define HOUT   64      // NH*OUTD
#define FUS    204     // 94 + 94 + 16
#define ALPHA  0.2f

#define NDEVG2  782    // ceil(100000/128) row-groups
#define NCOMBG2 64     // 8192/128 row-groups
#define KP      48     // K-pairs incl. zero pad (96 bf16 = 48 uints)

typedef unsigned short ushortT;
typedef unsigned int   uintT;
typedef ushortT ushort8v __attribute__((ext_vector_type(8)));
typedef short   short8  __attribute__((ext_vector_type(8)));
typedef float   float4v __attribute__((ext_vector_type(4)));

// ---------------- workspace layout (float slots) ----------------
// h_bf  : NDEV*64 bf16 = 3,200,000 @ 0   (12.8 MB)
// e_d   : NDEV*4       =   400,000 @ 3,200,000
// e_c   : NBATCH*4     =    32,768 @ 3,600,000
// wpack : 2*64*48 uint =     6,144 @ 3,632,768   (bf16x2-packed W^T, dev|comb)

template <typename T>
__device__ __forceinline__ const T* uniform_ptr(const T* p) {
  uint64_t v = (uint64_t)(uintptr_t)p;
  uint32_t lo = __builtin_amdgcn_readfirstlane((uint32_t)v);
  uint32_t hi = __builtin_amdgcn_readfirstlane((uint32_t)(v >> 32));
  return (const T*)(uintptr_t)(((uint64_t)hi << 32) | lo);
}

__device__ __forceinline__ float bf2f(ushortT u) {
  return __uint_as_float(((unsigned int)u) << 16);
}
__device__ __forceinline__ ushortT f2bf(float f) {
  unsigned int i = __float_as_uint(f);
  unsigned int r = i + 0x7FFFu + ((i >> 16) & 1u);  // round-to-nearest-even
  return (ushortT)(r >> 16);
}
__device__ __forceinline__ uintT pack2(float lo, float hi) {
  return ((uintT)f2bf(hi) << 16) | (uintT)f2bf(lo);
}

union FragU { uint4 u; short8 s; };

// ---------------- K0: pack W^T -> bf16x2 once (layout [n][p], n=h*16+o) -----
__global__ __launch_bounds__(256) void k_prep(
    const float* __restrict__ Wd, const float* __restrict__ Wc,
    uintT* __restrict__ wpack) {
  const int e = blockIdx.x * 256 + threadIdx.x;   // 0..6143
  if (e >= 2 * 64 * KP) return;
  const bool dev = e < 64 * KP;
  const int i = dev ? e : e - 64 * KP;
  const int n = i / KP, p = i - n * KP;
  const int h = n >> 4, o = n & 15;
  const float* __restrict__ Ws = dev ? Wd : Wc;
  uintT v = 0u;
  if (p < 47) {
    const float lo = Ws[(h * FEAT + 2 * p) * OUTD + o];
    const float hi = Ws[(h * FEAT + 2 * p + 1) * OUTD + o];
    v = pack2(lo, hi);
  }
  wpack[e] = v;
}

// ---------------- K1: X[row,94] @ W[94,64] via bf16 MFMA, 128 rows/block ----
// 4 waves; wave wv owns row-tiles {wv*16, 64+wv*16}, all 4 col-tiles.
// W staged once per block (prepacked); B-frags reused across both row-tiles.
__global__ __launch_bounds__(256, 2) void k_feat(
    const float* __restrict__ device_cont, const int* __restrict__ device_cat,
    const float* __restrict__ de0, const float* __restrict__ de1,
    const float* __restrict__ bd,
    const float* __restrict__ combin_cont, const int* __restrict__ combin_cat,
    const int* __restrict__ combin_idx,
    const float* __restrict__ ce0, const float* __restrict__ ce1,
    const float* __restrict__ bc,
    const float* __restrict__ aW, const uintT* __restrict__ wpack,
    ushortT* __restrict__ h_bf, float* __restrict__ e_d, float* __restrict__ e_c) {
  __shared__ uintT x_s[128 * KP];  // 24,576 B  [row][kpair]
  __shared__ uintT w_s[64 * KP];   // 12,288 B  [col n][kpair]
  __shared__ int   ci_s[128];

  const int tid  = threadIdx.x;
  const int lane = tid & 63;
  const int wv = __builtin_amdgcn_readfirstlane((int)(tid >> 6));
  const int blk = blockIdx.x;
  const bool devp = blk < NDEVG2;
  const int b0 = (devp ? blk : blk - NDEVG2) * 128;

  if (!devp && tid < 128) ci_s[tid] = combin_idx[b0 + tid];

  // ---- stage W: linear uint4 copy of the prepacked slab (768 uint4) ----
  {
    const uint4* __restrict__ wp =
        reinterpret_cast<const uint4*>(wpack + (devp ? 0 : 64 * KP));
#pragma unroll
    for (int t = 0; t < 3; ++t)
      reinterpret_cast<uint4*>(w_s)[t * 256 + tid] = wp[t * 256 + tid];
  }
  __syncthreads();  // ci_s visible

  // ---- stage x: cont pairs (128*31 = 3968) ----
  {
    const float* __restrict__ cont = devp ? device_cont : combin_cont;
#pragma unroll 1
    for (int e = tid; e < 128 * 31; e += 256) {
      const int r = e / 31, p = e - r * 31;
      const size_t srow = devp ? (size_t)min(b0 + r, NDEV - 1) : (size_t)ci_s[r];
      const float2 v = *reinterpret_cast<const float2*>(cont + srow * CONTF + 2 * p);
      x_s[r * KP + p] = pack2(v.x, v.y);
    }
  }
  // ---- stage embeddings: all 256 threads, one (row, table) each ----
  {
    const int r = tid >> 1, tb = tid & 1;  // r in 0..127
    const int srow = devp ? min(b0 + r, NDEV - 1) : ci_s[r];
    const int cidx = (devp ? device_cat : combin_cat)[2 * srow + tb];
    const float* __restrict__ ep =
        (tb ? (devp ? de1 : ce1) : (devp ? de0 : ce0)) + (size_t)cidx * EMB;
    uintT* __restrict__ dst = &x_s[r * KP + 31 + tb * 8];
#pragma unroll
    for (int k4 = 0; k4 < 4; ++k4) {
      const float4 v = reinterpret_cast<const float4*>(ep)[k4];
      dst[2 * k4 + 0] = pack2(v.x, v.y);
      dst[2 * k4 + 1] = pack2(v.z, v.w);
    }
  }
  if (tid < 128) x_s[tid * KP + 47] = 0u;         // k = 94,95 zero pad
  __syncthreads();

  // ---- MFMA compute ----
  const int m = lane & 15, q = lane >> 4;
  const float* bias = uniform_ptr(devp ? bd : bc);
  const float* aWl  = uniform_ptr(aW);

  float4v acc[2][NH];
#pragma unroll
  for (int ct = 0; ct < NH; ++ct) {
    const float bv = bias[ct * OUTD + m];
    acc[0][ct] = (float4v){bv, bv, bv, bv};
    acc[1][ct] = (float4v){bv, bv, bv, bv};
  }

  const uintT* xa0 = &x_s[(wv * 16 + m) * KP + q * 4];
  const uintT* xa1 = &x_s[(64 + wv * 16 + m) * KP + q * 4];
#pragma unroll
  for (int c = 0; c < 3; ++c) {                  // K chunks of 32
    FragU af0, af1;
    af0.u = *reinterpret_cast<const uint4*>(xa0 + c * 16);
    af1.u = *reinterpret_cast<const uint4*>(xa1 + c * 16);
#pragma unroll
    for (int ct = 0; ct < NH; ++ct) {
      FragU bf;
      bf.u = *reinterpret_cast<const uint4*>(&w_s[(ct * 16 + m) * KP + c * 16 + q * 4]);
      acc[0][ct] = __builtin_amdgcn_mfma_f32_16x16x32_bf16(af0.s, bf.s, acc[0][ct], 0, 0, 0);
      acc[1][ct] = __builtin_amdgcn_mfma_f32_16x16x32_bf16(af1.s, bf.s, acc[1][ct], 0, 0, 0);
    }
  }

  // ---- epilogue: e logits + h store, per row-tile ----
  const int aoff = devp ? OUTD : 0;
  float* __restrict__ eout = devp ? e_d : e_c;
#pragma unroll
  for (int rt = 0; rt < 2; ++rt) {
    const int rowq = b0 + rt * 64 + wv * 16 + q * 4;  // first of 4 rows
#pragma unroll
    for (int ct = 0; ct < NH; ++ct) {
      const float av = aWl[ct * 2 * OUTD + aoff + m];
      float e0 = acc[rt][ct][0] * av, e1 = acc[rt][ct][1] * av,
            e2 = acc[rt][ct][2] * av, e3 = acc[rt][ct][3] * av;
#pragma unroll
      for (int msk = 1; msk < 16; msk <<= 1) {
        e0 += __shfl_xor(e0, msk);
        e1 += __shfl_xor(e1, msk);
        e2 += __shfl_xor(e2, msk);
        e3 += __shfl_xor(e3, msk);
      }
      if (m == ct) {
        const float ev[4] = {e0, e1, e2, e3};
#pragma unroll
        for (int r = 0; r < 4; ++r)
          if (!devp || rowq + r < NDEV) eout[(size_t)(rowq + r) * NH + ct] = ev[r];
      }
    }
    if (devp) {
#pragma unroll
      for (int ct = 0; ct < NH; ++ct) {
#pragma unroll
        for (int r = 0; r < 4; ++r) {
          if (rowq + r < NDEV)
            h_bf[(size_t)(rowq + r) * HOUT + ct * OUTD + m] = f2bf(acc[rt][ct][r]);
        }
      }
    }
  }
}

// ---------------- K2: attention + fusion + MLP, fused (one wave = one row) --
// All LDS is per-wave ([wid]) -> no cross-wave dependency; wave_barrier()
// (scheduling fence) replaces __syncthreads: no vmcnt(0) drain, no inter-wave
// rendezvous. Intra-wave LDS ordering via compiler's conservative lgkmcnt
// (validated pattern: R6 k_mlp wave-local round-trip, absmax 0.0).
__global__ __launch_bounds__(256, 4) void k_attn(
    const int* __restrict__ neighbor_idx, const int* __restrict__ device_idx,
    const int* __restrict__ device_cat, const float* __restrict__ device_cont,
    const float* __restrict__ de0, const float* __restrict__ de1,
    const int* __restrict__ combin_idx, const int* __restrict__ combin_cat,
    const float* __restrict__ combin_cont,
    const float* __restrict__ ce0, const float* __restrict__ ce1,
    const ushortT* __restrict__ h_bf, const float* __restrict__ e_d,
    const float* __restrict__ e_c, const float* __restrict__ ab,
    const float* __restrict__ W1, const float* __restrict__ b1,
    const float* __restrict__ W2, const float* __restrict__ b2,
    const float* __restrict__ W3, const float* __restrict__ b3,
    const float* __restrict__ W4, const float* __restrict__ b4,
    float* __restrict__ out) {
  __shared__ __align__(16) float pb[4][NH][68];
  __shared__ __align__(16) int   nb[4][KNBR];
  __shared__ __align__(16) float hb[4][HOUT];
  __shared__ __align__(16) float fusb[4][208];   // fusion row (204 + pad)
  __shared__ __align__(16) float x1b[4][64];

  const int lane = threadIdx.x & 63;
  const int wid  = __builtin_amdgcn_readfirstlane((int)(threadIdx.x >> 6));
  const int b    = blockIdx.x * 4 + wid;

  // ---- phase A: softmax over neighbors (lane = k) ----
  const int nk = neighbor_idx[(size_t)b * KNBR + lane];
  const float4 ed4 = *reinterpret_cast<const float4*>(e_d + (size_t)nk * NH);
  const float4 ec4 = *reinterpret_cast<const float4*>(e_c + (size_t)b * NH);
  const float4 ab4 = *reinterpret_cast<const float4*>(ab);

  float v0 = ec4.x + ed4.x + ab4.x;
  float v1 = ec4.y + ed4.y + ab4.y;
  float v2 = ec4.z + ed4.z + ab4.z;
  float v3 = ec4.w + ed4.w + ab4.w;
  v0 = v0 > 0.f ? v0 : ALPHA * v0;
  v1 = v1 > 0.f ? v1 : ALPHA * v1;
  v2 = v2 > 0.f ? v2 : ALPHA * v2;
  v3 = v3 > 0.f ? v3 : ALPHA * v3;

  float m0 = v0, m1 = v1, m2 = v2, m3 = v3;
#pragma unroll
  for (int msk = 1; msk < 64; msk <<= 1) {
    m0 = fmaxf(m0, __shfl_xor(m0, msk));
    m1 = fmaxf(m1, __shfl_xor(m1, msk));
    m2 = fmaxf(m2, __shfl_xor(m2, msk));
    m3 = fmaxf(m3, __shfl_xor(m3, msk));
  }
  float p0 = expf(v0 - m0), p1 = expf(v1 - m1), p2 = expf(v2 - m2), p3 = expf(v3 - m3);
  float s0 = p0, s1 = p1, s2 = p2, s3 = p3;
#pragma unroll
  for (int msk = 1; msk < 64; msk <<= 1) {
    s0 += __shfl_xor(s0, msk);
    s1 += __shfl_xor(s1, msk);
    s2 += __shfl_xor(s2, msk);
    s3 += __shfl_xor(s3, msk);
  }
  p0 /= s0; p1 /= s1; p2 /= s2; p3 /= s3;

  pb[wid][0][lane] = p0;
  pb[wid][1][lane] = p1;
  pb[wid][2][lane] = p2;
  pb[wid][3][lane] = p3;
  nb[wid][lane]    = nk;

  // ---- phase A2: gather fusion features [comb 94 | dev 94] into LDS ----
  const int ci = combin_idx[b];
  const int cc0 = combin_cat[2 * ci], cc1 = combin_cat[2 * ci + 1];
  const int didx = device_idx[b];
  const int dc0 = device_cat[2 * didx], dc1 = device_cat[2 * didx + 1];
#pragma unroll
  for (int t = 0; t < 3; ++t) {
    const int i = lane + t * 64;
    if (i < 188) {
      float v;
      if (i < 62)       v = combin_cont[(size_t)ci * CONTF + i];
      else if (i < 78)  v = ce0[(size_t)cc0 * EMB + (i - 62)];
      else if (i < 94)  v = ce1[(size_t)cc1 * EMB + (i - 78)];
      else if (i < 156) v = device_cont[(size_t)didx * CONTF + (i - 94)];
      else if (i < 172) v = de0[(size_t)dc0 * EMB + (i - 156)];
      else              v = de1[(size_t)dc1 * EMB + (i - 172)];
      fusb[wid][i] = v;
    }
  }
  __builtin_amdgcn_wave_barrier();

  // ---- phase B: h_bf gather, lane = (q, c8) ----
  {
    const int q = lane >> 3, c8 = lane & 7;
    const int hq = c8 >> 1;
    float a[8];
#pragma unroll
    for (int i = 0; i < 8; ++i) a[i] = 0.f;
#pragma unroll
    for (int t = 0; t < 8; ++t) {
      const int k   = q * 8 + t;
      const int n   = nb[wid][k];
      const float p = pb[wid][hq][k];
      const ushort8v hv =
          *reinterpret_cast<const ushort8v*>(h_bf + (size_t)n * HOUT + c8 * 8);
#pragma unroll
      for (int i = 0; i < 8; ++i) a[i] = fmaf(p, bf2f(hv[i]), a[i]);
    }
#pragma unroll
    for (int msk = 8; msk < 64; msk <<= 1) {
#pragma unroll
      for (int i = 0; i < 8; ++i) a[i] += __shfl_xor(a[i], msk);
    }
    if (q == 0) {
#pragma unroll
      for (int i = 0; i < 8; ++i) a[i] = a[i] > 0.f ? a[i] : expm1f(a[i]);  // elu
      float4* hp = reinterpret_cast<float4*>(&hb[wid][c8 * 8]);
      hp[0] = make_float4(a[0], a[1], a[2], a[3]);
      hp[1] = make_float4(a[4], a[5], a[6], a[7]);
    }
  }
  __builtin_amdgcn_wave_barrier();

  // ---- phase C: attn_feats = head_out(64) @ W1(64x16) + b1 -> fusb[188..] --
  {
    const int j = lane & 15, gg = lane >> 4;
    float part = 0.f;
#pragma unroll
    for (int t = 0; t < 16; ++t)
      part = fmaf(hb[wid][gg * 16 + t], W1[(gg * 16 + t) * OUTD + j], part);
    part += __shfl_xor(part, 16);
    part += __shfl_xor(part, 32);
    if (lane < 16) fusb[wid][188 + lane] = part + b1[lane];
  }
  __builtin_amdgcn_wave_barrier();

  // ---- phase D: MLP layer 1 (204 -> 64), lane = output col ----
  float acc = b2[lane];
#pragma unroll 4
  for (int f = 0; f < FUS; ++f)
    acc = fmaf(fusb[wid][f], W2[f * 64 + lane], acc);  // ds broadcast + coalesced
  x1b[wid][lane] = fmaxf(acc, 0.f);
  __builtin_amdgcn_wave_barrier();

  // ---- layers 2+3 + sigmoid ----
  const int m = lane & 31, rh = lane >> 5;
  float x2 = rh ? 0.f : b3[m];
#pragma unroll 4
  for (int j = 0; j < 32; ++j) {
    const int jj = rh * 32 + j;
    x2 = fmaf(x1b[wid][jj], W3[jj * 32 + m], x2);
  }
  x2 += __shfl_xor(x2, 32);                      // combine j-halves
  float pL3 = fmaxf(x2, 0.f) * W4[m];
#pragma unroll
  for (int msk = 1; msk < 32; msk <<= 1) pL3 += __shfl_xor(pL3, msk);
  if (lane == 0) {
    const float z = pL3 + b4[0];
    out[b] = 1.f / (1.f + expf(-z));
  }
}

extern "C" void kernel_launch(void* const* d_in, const int* in_sizes, int n_in,
                              void* d_out, int out_size, void* d_ws, size_t ws_size,
                              hipStream_t stream) {
  const float* combin_cont  = (const float*)d_in[0];
  const int*   combin_cat   = (const int*)d_in[1];
  const float* device_cont  = (const float*)d_in[2];
  const int*   device_cat   = (const int*)d_in[3];
  const int*   combin_idx   = (const int*)d_in[4];
  const int*   device_idx   = (const int*)d_in[5];
  const int*   neighbor_idx = (const int*)d_in[6];
  const float* ce0 = (const float*)d_in[7];
  const float* ce1 = (const float*)d_in[8];
  const float* de0 = (const float*)d_in[9];
  const float* de1 = (const float*)d_in[10];
  const float* Wc  = (const float*)d_in[11];
  const float* bc  = (const float*)d_in[12];
  const float* Wd  = (const float*)d_in[13];
  const float* bd  = (const float*)d_in[14];
  const float* aW  = (const float*)d_in[15];
  const float* ab  = (const float*)d_in[16];
  const float* W1  = (const float*)d_in[17];
  const float* b1  = (const float*)d_in[18];
  const float* W2  = (const float*)d_in[19];
  const float* b2  = (const float*)d_in[20];
  const float* W3  = (const float*)d_in[21];
  const float* b3  = (const float*)d_in[22];
  const float* W4  = (const float*)d_in[23];
  const float* b4  = (const float*)d_in[24];

  float* ws  = (float*)d_ws;
  ushortT* h_bf = (ushortT*)ws;
  float* e_d = ws + 3200000;
  float* e_c = ws + 3600000;
  uintT* wpack = (uintT*)(ws + 3632768);

  k_prep<<<24, 256, 0, stream>>>(Wd, Wc, wpack);
  k_feat<<<NDEVG2 + NCOMBG2, 256, 0, stream>>>(
      device_cont, device_cat, de0, de1, bd,
      combin_cont, combin_cat, combin_idx, ce0, ce1, bc, aW, wpack,
      h_bf, e_d, e_c);
  k_attn<<<2048, 256, 0, stream>>>(
      neighbor_idx, device_idx, device_cat, device_cont, de0, de1,
      combin_idx, combin_cat, combin_cont, ce0, ce1,
      h_bf, e_d, e_c, ab, W1, b1, W2, b2, W3, b3, W4, b4, (float*)d_out);
}